// Round 3
// baseline (206.612 us; speedup 1.0000x reference)
//
#include <hip/hip_runtime.h>
#include <hip/hip_bf16.h>
#include <stdint.h>

namespace {
constexpr int kB = 8, kT = 16, kN = 1000, kF = 16;
constexpr int kE = 16000;
constexpr int kH = 4, kHD = 128;
constexpr int kHL = 64, kOUT = 8;
constexpr int kG = kB * kT;
constexpr float kNeg = 0.2f;
constexpr int kNB = 25;                  // gat blocks per graph (R0/R2 operating point)
constexpr int kNPB = 40;                 // nodes per gat block
constexpr int kPre = 2007;               // precompute blocks: 41+2007 = 2048 = 8 clean rounds
constexpr int kNPW = 16;                 // nodes per precompute wave
constexpr int kBCAP = 64;                // bucket capacity per node (Poisson(16) tail ~1e-18)

// Canonical bf16 weights (for lstm_head + bg), element offsets:
constexpr size_t CX_WG   = 0;                       // 2048 (layout only)
constexpr size_t CX_ATS  = CX_WG   + 2048;
constexpr size_t CX_ATD  = CX_ATS  + 128;
constexpr size_t CX_BG   = CX_ATD  + 128;
constexpr size_t CX_WIH  = CX_BG   + 128;
constexpr size_t CX_WHH  = CX_WIH  + 32768;
constexpr size_t CX_BIH  = CX_WHH  + 16384;
constexpr size_t CX_BHH  = CX_BIH  + 256;
constexpr size_t CX_WCLF = CX_BHH  + 256;
constexpr size_t CX_BCLF = CX_WCLF + 512;
constexpr size_t CX_TOTAL = CX_BCLF + 8;

// Workspace byte offsets (256-aligned)
constexpr size_t OFF_FLAG  = 0;
constexpr size_t OFF_ROW   = 256;                    // deg[1000] (bucket) | row[1001] (fallback)
constexpr size_t OFF_COL   = 4352;                   // col[16000] (fallback only)
constexpr size_t OFF_POOL  = 68608;                  // float[kG*kHD] (atomic fallback)
constexpr size_t OFF_CANON = 134400;                 // bf16[CX_TOTAL]
constexpr size_t OFF_AS    = 239872;
// a_s: 128*16000 B, a_d: 128*16000 B, xp(bf16): 128*256000 B
constexpr size_t OFF_PPART = OFF_AS + (size_t)kG * 288000;     // 37,103,872
constexpr size_t PPART_BYTES = (size_t)kG * kNB * kHD * 4;     // 1,638,400
constexpr size_t OFF_BUCKET = OFF_PPART + PPART_BYTES;         // 38,742,272
constexpr size_t BUCKET_BYTES = (size_t)kN * kBCAP * 4;        // 256,000

constexpr int kSetupBlocks = 41;   // 0-7 convert, 8 zero-pool, 9-40 scatter (or 9=serial CSR)
}

typedef float v2f __attribute__((ext_vector_type(2)));

__device__ __forceinline__ float bf2f(unsigned short u) {
    return __uint_as_float(((uint32_t)u) << 16);
}
__device__ __forceinline__ float blo(uint32_t u) { return __uint_as_float(u << 16); }
__device__ __forceinline__ float bhi(uint32_t u) { return __uint_as_float(u & 0xffff0000u); }
__device__ __forceinline__ unsigned short f2bf(float f) {
    uint32_t u = __float_as_uint(f);
    uint32_t r = (u + 0x7fff + ((u >> 16) & 1)) >> 16;
    return (unsigned short)r;
}
__device__ __forceinline__ float sigm(float x) { return 1.f / (1.f + __expf(-x)); }

// dtype probe: bf16 N(0,1) shorts are ~100% in exponent band [97,143];
// fp32 viewed as shorts ~55-59%. 512 samples is plenty of separation.
__device__ __forceinline__ int detect_isf(const unsigned short* xs, int t,
                                          int nthr, int* sh_cnt) {
    if (t == 0) *sh_cnt = 0;
    __syncthreads();
    int loc = 0;
    for (int i = t; i < 512; i += nthr) {
        unsigned short u = xs[i];
        int ex = (u >> 7) & 0xff;
        if (u == 0 || (ex >= 97 && ex <= 143)) loc++;
    }
    atomicAdd(sh_cnt, loc);
    __syncthreads();
    return (*sh_cnt >= 410) ? 0 : 1;
}

struct ConvArgs {
    const unsigned short* src[10];
    int n[10];
};

// ---------------------------------------------------------------------------
// Kernel 1 (mega-setup, 41+2007 = 2048 blocks x 256 — exactly 8 rounds/CU):
//  blocks 0-7:  convert weights to canonical bf16 (8-way split)
//  block 8:     zero pooled (atomic fallback only)
//  blocks 9-40: PARALLEL edge scatter into fixed-cap buckets (deg via global
//               atomicAdd; deg pre-zeroed by hipMemsetAsync). R2 evidence:
//               replacing the serial CSR cut total 241->201 us.
//               Fallback (!use_bucket): block 9 runs the old serial CSR.
//  blocks 41+:  wave-per-node precompute (W_gat in 32 VGPRs/lane, xp packed
//               stores, a_s/a_d via 16-lane shfl_xor butterfly; no LDS).
//               16 nodes/wave: halves block duration (tail smoothing).
// ---------------------------------------------------------------------------
__global__ __launch_bounds__(256) void mega_setup(
        const void* __restrict__ xraw, const int* __restrict__ ei,
        ConvArgs ca,
        const unsigned short* __restrict__ WgR,
        const unsigned short* __restrict__ atsR,
        const unsigned short* __restrict__ atdR,
        int* __restrict__ flag, int* __restrict__ rowdeg, int* __restrict__ col,
        int* __restrict__ bucket, int use_bucket,
        unsigned short* __restrict__ canon,
        unsigned short* __restrict__ xp_all,
        float* __restrict__ as_all, float* __restrict__ ad_all,
        unsigned int* __restrict__ pooled) {
    const int t = threadIdx.x;
    const unsigned short* xs = (const unsigned short*)xraw;

    if (blockIdx.x < 8) {
        // ================= weight conversion (8-way split) =================
        __shared__ int dcnt;
        const int isf = detect_isf(xs, t, 256, &dcnt);
        if (blockIdx.x == 0 && t == 0) *flag = isf;
        const int gid = (int)blockIdx.x * 256 + t;         // 0..2047
        size_t base = 0;
        for (int s = 0; s < 10; ++s) {
            const int n = ca.n[s];
            if (isf) {
                const float* fp = (const float*)ca.src[s];
                for (int i = gid; i < n; i += 2048) canon[base + i] = f2bf(fp[i]);
            } else {
                const unsigned short* sp = ca.src[s];
                for (int i = gid; i < n; i += 2048) canon[base + i] = sp[i];
            }
            base += (size_t)n;
        }
    } else if (blockIdx.x == 8) {
        for (int i = t; i < kG * kHD; i += 256) pooled[i] = 0u;
    } else if (blockIdx.x < kSetupBlocks) {
        if (use_bucket) {
            // ============ parallel bucket scatter (32 blocks) ============
            const int gid = (int)(blockIdx.x - 9) * 256 + t;   // 0..8191
            const int* srcp = ei;
            const int* dstp = ei + kE;
            for (int e = gid; e < kE; e += 32 * 256) {
                const int d = dstp[e];
                const int pos = atomicAdd(&rowdeg[d], 1);
                if (pos < kBCAP) bucket[d * kBCAP + pos] = srcp[e];
            }
        } else if (blockIdx.x == 9) {
            // ============ serial CSR fallback (single block) ============
            __shared__ int cnt[1024];
            __shared__ int wtot[4];
            const int lane = t & 63, w = t >> 6;
            for (int i = t; i < 1024; i += 256) cnt[i] = 0;
            __syncthreads();
            const int* dst = ei + kE;
            for (int e = t; e < kE; e += 256) atomicAdd(&cnt[dst[e]], 1);
            __syncthreads();
            const int n0 = 4 * t;
            int c0 = cnt[n0], c1 = cnt[n0 + 1], c2 = cnt[n0 + 2], c3 = cnt[n0 + 3];
            int s0 = c0, s1 = s0 + c1, s2 = s1 + c2, s3 = s2 + c3;
            int tot = s3;
#pragma unroll
            for (int sft = 1; sft < 64; sft <<= 1) {
                int v = __shfl_up(tot, sft, 64);
                if (lane >= sft) tot += v;
            }
            if (lane == 63) wtot[w] = tot;
            __syncthreads();
            int wexcl = 0;
            for (int j = 0; j < w; ++j) wexcl += wtot[j];
            const int excl = wexcl + tot - s3;
            if (t == 0) rowdeg[0] = 0;
            if (n0 < kN) {
                rowdeg[n0 + 1] = excl + s0;
                rowdeg[n0 + 2] = excl + s1;
                rowdeg[n0 + 3] = excl + s2;
                rowdeg[n0 + 4] = excl + s3;
            }
            __syncthreads();
            cnt[n0] = excl; cnt[n0 + 1] = excl + s0;
            cnt[n0 + 2] = excl + s1; cnt[n0 + 3] = excl + s2;
            __syncthreads();
            for (int e = t; e < kE; e += 256) {
                int d0 = dst[e];
                int pos = atomicAdd(&cnt[d0], 1);
                col[pos] = ei[e];
            }
        }
    } else {
        // ================= wave-per-node precompute =================
        __shared__ int dcnt;
        const int isf = detect_isf(xs, t, 256, &dcnt);
        const int lane = t & 63;
        const int wv = t >> 6;
        const int wid = (int)(blockIdx.x - kSetupBlocks) * 4 + wv;  // 0..8027

        // per-lane weights: channel pair c0 = 2*lane, c0+1
        float wA[kF], wB[kF];
        float as0, as1, ad0, ad1;
        if (isf) {
            const float* wf = (const float*)WgR;
#pragma unroll
            for (int f = 0; f < kF; ++f) {
                const float2 wp = ((const float2*)(wf + (size_t)f * kHD))[lane];
                wA[f] = wp.x; wB[f] = wp.y;
            }
            const float2 sv = ((const float2*)atsR)[lane];
            as0 = sv.x; as1 = sv.y;
            const float2 dv2 = ((const float2*)atdR)[lane];
            ad0 = dv2.x; ad1 = dv2.y;
        } else {
            const uint32_t* w32 = (const uint32_t*)WgR;
#pragma unroll
            for (int f = 0; f < kF; ++f) {
                const uint32_t u = w32[f * 64 + lane];
                wA[f] = blo(u); wB[f] = bhi(u);
            }
            const uint32_t us = ((const uint32_t*)atsR)[lane];
            as0 = blo(us); as1 = bhi(us);
            const uint32_t ud = ((const uint32_t*)atdR)[lane];
            ad0 = blo(ud); ad1 = bhi(ud);
        }

        uint32_t* xp32 = (uint32_t*)xp_all;
        const int nEnd = min(wid * kNPW + kNPW, kG * kN);
        for (int node = wid * kNPW; node < nEnd; ++node) {
            float xv[kF];
            if (isf) {
                const float4* xr4 = (const float4*)((const float*)xraw + (size_t)node * kF);
                const float4 x0 = xr4[0], x1 = xr4[1], x2 = xr4[2], x3 = xr4[3];
                xv[0] = x0.x; xv[1] = x0.y; xv[2]  = x0.z; xv[3]  = x0.w;
                xv[4] = x1.x; xv[5] = x1.y; xv[6]  = x1.z; xv[7]  = x1.w;
                xv[8] = x2.x; xv[9] = x2.y; xv[10] = x2.z; xv[11] = x2.w;
                xv[12] = x3.x; xv[13] = x3.y; xv[14] = x3.z; xv[15] = x3.w;
            } else {
                const uint4* xr4 = (const uint4*)(xs + (size_t)node * kF);
                const uint4 q0 = xr4[0], q1 = xr4[1];
                xv[0]  = blo(q0.x); xv[1]  = bhi(q0.x);
                xv[2]  = blo(q0.y); xv[3]  = bhi(q0.y);
                xv[4]  = blo(q0.z); xv[5]  = bhi(q0.z);
                xv[6]  = blo(q0.w); xv[7]  = bhi(q0.w);
                xv[8]  = blo(q1.x); xv[9]  = bhi(q1.x);
                xv[10] = blo(q1.y); xv[11] = bhi(q1.y);
                xv[12] = blo(q1.z); xv[13] = bhi(q1.z);
                xv[14] = blo(q1.w); xv[15] = bhi(q1.w);
            }
            float vA = 0.f, vB = 0.f;
#pragma unroll
            for (int f = 0; f < kF; ++f) {
                vA = fmaf(xv[f], wA[f], vA);
                vB = fmaf(xv[f], wB[f], vB);
            }
            xp32[(size_t)node * 64 + lane] =
                (uint32_t)f2bf(vA) | ((uint32_t)f2bf(vB) << 16);
            // a_s/a_d: per-head (16-lane) butterfly reduce
            float aS = vA * as0 + vB * as1;
            float aD = vA * ad0 + vB * ad1;
#pragma unroll
            for (int sft = 1; sft < 16; sft <<= 1) {
                aS += __shfl_xor(aS, sft, 64);
                aD += __shfl_xor(aD, sft, 64);
            }
            if ((lane & 15) == 0) {
                as_all[(size_t)node * kH + (lane >> 4)] = aS;
                ad_all[(size_t)node * kH + (lane >> 4)] = aD;
            }
        }
    }
}

// ---------------------------------------------------------------------------
// Kernel 2: GAT edge-softmax aggregation + relu + max-pool.
// R2 operating point (3200 blocks, 40 nodes/block, 10 iters x 4 waves).
// R3: fused {col,alpha} float2 LDS (1 ds_read_b64 replaces 2 b32; head
// stride 68 f2 = 136 floats == 8 mod 32 -> the 16 distinct (head,sub) b64
// reads tile all 32 banks exactly once: conflict-free). Accumulators as
// ext_vector float2 to let the backend form v_pk_fma_f32.
// ---------------------------------------------------------------------------
__global__ __launch_bounds__(256) void gat_aggregate(
        const int* __restrict__ rowdeg, const int* __restrict__ col,
        const int* __restrict__ bucket, int use_bucket,
        const unsigned short* __restrict__ xp,
        const float* __restrict__ a_s, const float* __restrict__ a_d,
        const unsigned short* __restrict__ bg,
        unsigned int* __restrict__ pooled,
        float* __restrict__ part, int use_part) {
    __shared__ float2 colal[4][4][68];   // [wave][head][edge] {col_bits, alpha}
    __shared__ float pm[4][kHD];

    const int w = threadIdx.x >> 6;
    const int lane = threadIdx.x & 63;
    const int sub = lane >> 4;          // edge subgroup 0..3
    const int cl = lane & 15;           // channels cl*8 .. cl*8+7
    const int hh = cl >> 2;
    const int xcd = blockIdx.x & 7;
    const int j = blockIdx.x >> 3;      // 0..399
    const int gl = xcd + 8 * (j / kNB); // graph-major within XCD
    const int blk = j % kNB;            // 0..24
    const size_t gn = (size_t)gl * kN;
    const char* xpcl = (const char*)(xp + gn * kHD) + cl * 16;
    const float4* as4 = (const float4*)a_s + gn;
    const float4* ad4 = (const float4*)a_d + gn;
    const uint32_t* bg32 = (const uint32_t*)bg;
    float bgv[8];
#pragma unroll
    for (int jb = 0; jb < 4; ++jb) {
        uint32_t u = bg32[cl * 4 + jb];
        bgv[2 * jb] = blo(u);
        bgv[2 * jb + 1] = bhi(u);
    }
    float pool[8];
#pragma unroll
    for (int jb = 0; jb < 8; ++jb) pool[jb] = 0.f;

    for (int it = 0; it < 10; ++it) {
        const int n = blk * kNPB + it * 4 + w;
        int r0, deg;
        if (use_bucket) {
            r0 = n * kBCAP;
            deg = min(rowdeg[n], kBCAP);
        } else {
            r0 = rowdeg[n];
            deg = rowdeg[n + 1] - r0;
        }
        const int* colb = use_bucket ? bucket : col;
        const int E = deg + 1;          // + self loop (index deg)
        const float4 dv = ad4[n];
        v2f acc2[4];
#pragma unroll
        for (int jb = 0; jb < 4; ++jb) acc2[jb] = (v2f){0.f, 0.f};
        float dh = 0.f;

        for (int base = 0; base < E; base += 64) {
            const int cnt = min(64, E - base);
            const int cntP = (cnt + 3) & ~3;
            // ---- phase 1: lanes = edges (pad lanes get alpha 0) ----
            if (lane < cntP) {
                const int eg = base + lane;
                const bool act = lane < cnt;
                const int s = (act && eg < deg) ? colb[r0 + eg] : n;
                float p0 = 0.f, p1 = 0.f, p2 = 0.f, p3 = 0.f;
                if (act) {
                    const float4 av = as4[s];
                    float t0 = av.x + dv.x, t1 = av.y + dv.y;
                    float t2 = av.z + dv.z, t3 = av.w + dv.w;
                    t0 = t0 > 0.f ? t0 : kNeg * t0;
                    t1 = t1 > 0.f ? t1 : kNeg * t1;
                    t2 = t2 > 0.f ? t2 : kNeg * t2;
                    t3 = t3 > 0.f ? t3 : kNeg * t3;
                    p0 = __expf(t0); p1 = __expf(t1);
                    p2 = __expf(t2); p3 = __expf(t3);
                }
                const float cf = __int_as_float(s << 8);   // xp row byte offset
                colal[w][0][lane] = make_float2(cf, p0);
                colal[w][1][lane] = make_float2(cf, p1);
                colal[w][2][lane] = make_float2(cf, p2);
                colal[w][3][lane] = make_float2(cf, p3);
            }
            // wave-synchronous LDS use; branch-free inner loop
            for (int e0 = 0; e0 < cntP; e0 += 4) {
                const float2 ca = colal[w][hh][e0 + sub];
                const uint4 u = *(const uint4*)(xpcl + __float_as_int(ca.x));
                const float al = ca.y;
                const v2f al2 = {al, al};
                const v2f x0 = {blo(u.x), bhi(u.x)};
                const v2f x1 = {blo(u.y), bhi(u.y)};
                const v2f x2 = {blo(u.z), bhi(u.z)};
                const v2f x3 = {blo(u.w), bhi(u.w)};
                acc2[0] += al2 * x0;
                acc2[1] += al2 * x1;
                acc2[2] += al2 * x2;
                acc2[3] += al2 * x3;
                dh += al;
            }
        }
        float acc[8];
#pragma unroll
        for (int jb = 0; jb < 4; ++jb) {
            acc[2 * jb] = acc2[jb].x;
            acc[2 * jb + 1] = acc2[jb].y;
        }
#pragma unroll
        for (int jb = 0; jb < 8; ++jb) {
            acc[jb] += __shfl_xor(acc[jb], 16, 64);
            acc[jb] += __shfl_xor(acc[jb], 32, 64);
        }
        dh += __shfl_xor(dh, 16, 64);
        dh += __shfl_xor(dh, 32, 64);
        const float inv = 1.f / dh;
#pragma unroll
        for (int jb = 0; jb < 8; ++jb) {
            const float o = acc[jb] * inv + bgv[jb];
            pool[jb] = fmaxf(pool[jb], o > 0.f ? o : 0.f);
        }
    }
    if (sub == 0) {
#pragma unroll
        for (int jb = 0; jb < 8; ++jb) pm[w][cl * 8 + jb] = pool[jb];
    }
    __syncthreads();
    if (w == 0 && sub == 0) {
        if (use_part) {
            float* dst = part + ((size_t)gl * kNB + blk) * kHD;
#pragma unroll
            for (int jb = 0; jb < 8; ++jb) {
                const int c = cl * 8 + jb;
                dst[c] = fmaxf(fmaxf(pm[0][c], pm[1][c]), fmaxf(pm[2][c], pm[3][c]));
            }
        } else {
            const size_t gp = (size_t)gl * kHD;
#pragma unroll
            for (int jb = 0; jb < 8; ++jb) {
                const int c = cl * 8 + jb;
                float vmax = fmaxf(fmaxf(pm[0][c], pm[1][c]), fmaxf(pm[2][c], pm[3][c]));
                atomicMax(pooled + gp + c, __float_as_uint(vmax));
            }
        }
    }
}

// ---------------------------------------------------------------------------
// Kernel 3: LSTM over T=16 + classifier. One block per batch row b.
// xt load folds the kNB-way partial-max reduce when use_part=1.
// ---------------------------------------------------------------------------
__global__ __launch_bounds__(256) void lstm_head(
        const float* __restrict__ pooled, const float* __restrict__ part,
        int use_part,
        const unsigned short* __restrict__ Wih,
        const unsigned short* __restrict__ Whh,
        const unsigned short* __restrict__ bih,
        const unsigned short* __restrict__ bhh,
        const unsigned short* __restrict__ Wclf,
        const unsigned short* __restrict__ bclf,
        const int* __restrict__ flag,
        void* __restrict__ out) {
    const int b = blockIdx.x;
    const int r = threadIdx.x;
    __shared__ float xt[kHD];
    __shared__ float hs[kHL];
    __shared__ float gates[4 * kHL];

    uint32_t wih[64];
    const uint32_t* pw = (const uint32_t*)(Wih + (size_t)r * kHD);
#pragma unroll
    for (int j = 0; j < 64; ++j) wih[j] = pw[j];
    uint32_t whh[32];
    const uint32_t* ph = (const uint32_t*)(Whh + (size_t)r * kHL);
#pragma unroll
    for (int j = 0; j < 32; ++j) whh[j] = ph[j];
    const float bias = bf2f(bih[r]) + bf2f(bhh[r]);

    float c_st = 0.f;
    if (r < kHL) hs[r] = 0.f;
    __syncthreads();

    for (int t = 0; t < kT; ++t) {
        const size_t g = (size_t)b * kT + t;
        if (r < kHD) {
            if (use_part) {
                const float* ps = part + g * kNB * kHD + r;
                float v = ps[0];
#pragma unroll
                for (int k = 1; k < kNB; ++k) v = fmaxf(v, ps[(size_t)k * kHD]);
                xt[r] = v;
            } else {
                xt[r] = pooled[g * kHD + r];
            }
        }
        __syncthreads();
        float a0 = 0.f, a1 = 0.f, a2 = 0.f, a3 = 0.f;
#pragma unroll
        for (int j = 0; j < 64; j += 4) {
            uint32_t u0 = wih[j], u1 = wih[j + 1], u2 = wih[j + 2], u3 = wih[j + 3];
            a0 += blo(u0) * xt[2 * j + 0] + bhi(u0) * xt[2 * j + 1];
            a1 += blo(u1) * xt[2 * j + 2] + bhi(u1) * xt[2 * j + 3];
            a2 += blo(u2) * xt[2 * j + 4] + bhi(u2) * xt[2 * j + 5];
            a3 += blo(u3) * xt[2 * j + 6] + bhi(u3) * xt[2 * j + 7];
        }
#pragma unroll
        for (int j = 0; j < 32; j += 4) {
            uint32_t u0 = whh[j], u1 = whh[j + 1], u2 = whh[j + 2], u3 = whh[j + 3];
            a0 += blo(u0) * hs[2 * j + 0] + bhi(u0) * hs[2 * j + 1];
            a1 += blo(u1) * hs[2 * j + 2] + bhi(u1) * hs[2 * j + 3];
            a2 += blo(u2) * hs[2 * j + 4] + bhi(u2) * hs[2 * j + 5];
            a3 += blo(u3) * hs[2 * j + 6] + bhi(u3) * hs[2 * j + 7];
        }
        gates[r] = bias + (a0 + a1) + (a2 + a3);
        __syncthreads();
        if (r < kHL) {
            const float iv = sigm(gates[r]);
            const float fv = sigm(gates[kHL + r]);
            const float gv = tanhf(gates[2 * kHL + r]);
            const float ov = sigm(gates[3 * kHL + r]);
            c_st = fv * c_st + iv * gv;
            hs[r] = ov * tanhf(c_st);
        }
        __syncthreads();
    }
    if (r < kOUT) {
        float acc = bf2f(bclf[r]);
#pragma unroll
        for (int k = 0; k < kHL; ++k) acc += hs[k] * bf2f(Wclf[r * kHL + k]);
        if (*flag) ((float*)out)[b * kOUT + r] = acc;
        else ((__hip_bfloat16*)out)[b * kOUT + r] = __float2bfloat16(acc);
    }
}

// ---------------------------------------------------------------------------
extern "C" void kernel_launch(void* const* d_in, const int* in_sizes, int n_in,
                              void* d_out, int out_size, void* d_ws, size_t ws_size,
                              hipStream_t stream) {
    const int* ei = (const int*)d_in[1];

    char* ws = (char*)d_ws;
    int*            flag   = (int*)(ws + OFF_FLAG);
    int*            rowdeg = (int*)(ws + OFF_ROW);
    int*            colv   = (int*)(ws + OFF_COL);
    unsigned int*   pooled = (unsigned int*)(ws + OFF_POOL);
    unsigned short* canon  = (unsigned short*)(ws + OFF_CANON);

    unsigned short* cBg   = canon + CX_BG;
    unsigned short* cWih  = canon + CX_WIH;
    unsigned short* cWhh  = canon + CX_WHH;
    unsigned short* cBih  = canon + CX_BIH;
    unsigned short* cBhh  = canon + CX_BHH;
    unsigned short* cWclf = canon + CX_WCLF;
    unsigned short* cBclf = canon + CX_BCLF;

    float*          a_s = (float*)(ws + OFF_AS);
    float*          a_d = (float*)(ws + OFF_AS + (size_t)kG * 16000);
    unsigned short* xp  = (unsigned short*)(ws + OFF_AS + (size_t)kG * 32000);

    // ws_size is fixed per session -> flags constant -> graph-capture safe
    const int use_part   = (ws_size >= OFF_PPART + PPART_BYTES) ? 1 : 0;
    const int use_bucket = (ws_size >= OFF_BUCKET + BUCKET_BYTES) ? 1 : 0;
    float* part   = (float*)(ws + OFF_PPART);
    int*   bucket = (int*)(ws + OFF_BUCKET);

    ConvArgs ca;
    const int sizes[10] = {2048, 128, 128, 128, 32768, 16384, 256, 256, 512, 8};
    const int which[10] = {2, 3, 4, 5, 6, 7, 8, 9, 10, 11};
    for (int i = 0; i < 10; ++i) {
        ca.src[i] = (const unsigned short*)d_in[which[i]];
        ca.n[i] = sizes[i];
    }

    // zero deg (bucket path) — 4 KB, graph-capture-safe memset node
    hipMemsetAsync(ws + OFF_ROW, 0, 4096, stream);

    mega_setup<<<kSetupBlocks + kPre, 256, 0, stream>>>(
        d_in[0], ei, ca,
        (const unsigned short*)d_in[2], (const unsigned short*)d_in[3],
        (const unsigned short*)d_in[4],
        flag, rowdeg, colv, bucket, use_bucket, canon, xp, a_s, a_d, pooled);
    gat_aggregate<<<kG * kNB, 256, 0, stream>>>(rowdeg, colv, bucket, use_bucket,
                                                xp, a_s, a_d, cBg,
                                                pooled, part, use_part);
    lstm_head<<<kB, 256, 0, stream>>>((const float*)pooled, part, use_part,
                                      cWih, cWhh, cBih, cBhh,
                                      cWclf, cBclf, flag, d_out);
}

// Round 4
// 200.581 us; speedup vs baseline: 1.0301x; 1.0301x over previous
//
#include <hip/hip_runtime.h>
#include <hip/hip_bf16.h>
#include <stdint.h>

namespace {
constexpr int kB = 8, kT = 16, kN = 1000, kF = 16;
constexpr int kE = 16000;
constexpr int kH = 4, kHD = 128;
constexpr int kHL = 64, kOUT = 8;
constexpr int kG = kB * kT;
constexpr float kNeg = 0.2f;
constexpr int kNB = 25;                  // gat blocks per graph (R0/R2 operating point)
constexpr int kNPB = 40;                 // nodes per gat block
constexpr int kPre = 1024;               // precompute blocks (R2 config; R3's 2007 cost ~6us)
constexpr int kNPW = 32;                 // nodes per precompute wave (R2 config)
constexpr int kBCAP = 64;                // bucket capacity per node (Poisson(16) tail ~1e-18)

// Canonical bf16 weights (for lstm_head + bg), element offsets:
constexpr size_t CX_WG   = 0;                       // 2048 (layout only)
constexpr size_t CX_ATS  = CX_WG   + 2048;
constexpr size_t CX_ATD  = CX_ATS  + 128;
constexpr size_t CX_BG   = CX_ATD  + 128;
constexpr size_t CX_WIH  = CX_BG   + 128;
constexpr size_t CX_WHH  = CX_WIH  + 32768;
constexpr size_t CX_BIH  = CX_WHH  + 16384;
constexpr size_t CX_BHH  = CX_BIH  + 256;
constexpr size_t CX_WCLF = CX_BHH  + 256;
constexpr size_t CX_BCLF = CX_WCLF + 512;
constexpr size_t CX_TOTAL = CX_BCLF + 8;

// Workspace byte offsets (256-aligned)
constexpr size_t OFF_FLAG  = 0;
constexpr size_t OFF_ROW   = 256;                    // deg[1000] (bucket) | row[1001] (fallback)
constexpr size_t OFF_COL   = 4352;                   // col[16000] (fallback only)
constexpr size_t OFF_POOL  = 68608;                  // float[kG*kHD] (atomic fallback)
constexpr size_t OFF_CANON = 134400;                 // bf16[CX_TOTAL]
constexpr size_t OFF_AS    = 239872;
// a_s: 128*16000 B, a_d: 128*16000 B, xp(bf16): 128*256000 B
constexpr size_t OFF_PPART = OFF_AS + (size_t)kG * 288000;     // 37,103,872
constexpr size_t PPART_BYTES = (size_t)kG * kNB * kHD * 4;     // 1,638,400
constexpr size_t OFF_BUCKET = OFF_PPART + PPART_BYTES;         // 38,742,272
constexpr size_t BUCKET_BYTES = (size_t)kN * kBCAP * 4;        // 256,000

constexpr int kSetupBlocks = 41;   // 0-7 convert, 8 zero-pool, 9-40 scatter (or 9=serial CSR)
}

typedef float v2f __attribute__((ext_vector_type(2)));

__device__ __forceinline__ float bf2f(unsigned short u) {
    return __uint_as_float(((uint32_t)u) << 16);
}
__device__ __forceinline__ float blo(uint32_t u) { return __uint_as_float(u << 16); }
__device__ __forceinline__ float bhi(uint32_t u) { return __uint_as_float(u & 0xffff0000u); }
__device__ __forceinline__ unsigned short f2bf(float f) {
    uint32_t u = __float_as_uint(f);
    uint32_t r = (u + 0x7fff + ((u >> 16) & 1)) >> 16;
    return (unsigned short)r;
}
__device__ __forceinline__ float sigm(float x) { return 1.f / (1.f + __expf(-x)); }

// dtype probe: bf16 N(0,1) shorts are ~100% in exponent band [97,143];
// fp32 viewed as shorts ~55-59%. 512 samples is plenty of separation.
__device__ __forceinline__ int detect_isf(const unsigned short* xs, int t,
                                          int nthr, int* sh_cnt) {
    if (t == 0) *sh_cnt = 0;
    __syncthreads();
    int loc = 0;
    for (int i = t; i < 512; i += nthr) {
        unsigned short u = xs[i];
        int ex = (u >> 7) & 0xff;
        if (u == 0 || (ex >= 97 && ex <= 143)) loc++;
    }
    atomicAdd(sh_cnt, loc);
    __syncthreads();
    return (*sh_cnt >= 410) ? 0 : 1;
}

struct ConvArgs {
    const unsigned short* src[10];
    int n[10];
};

// ---------------------------------------------------------------------------
// Kernel 1 (mega-setup, 41+1024 blocks x 256 — R2 configuration):
//  blocks 0-7:  convert weights to canonical bf16 (8-way split)
//  block 8:     zero pooled (atomic fallback only)
//  blocks 9-40: PARALLEL edge scatter into fixed-cap buckets (deg via global
//               atomicAdd; deg pre-zeroed by hipMemsetAsync). R2 evidence:
//               replacing the serial CSR cut total 241->201 us.
//               Fallback (!use_bucket): block 9 runs the old serial CSR.
//  blocks 41+:  wave-per-node precompute (W_gat in 32 VGPRs/lane, xp packed
//               stores, a_s/a_d via 16-lane shfl_xor butterfly; no LDS).
// ---------------------------------------------------------------------------
__global__ __launch_bounds__(256) void mega_setup(
        const void* __restrict__ xraw, const int* __restrict__ ei,
        ConvArgs ca,
        const unsigned short* __restrict__ WgR,
        const unsigned short* __restrict__ atsR,
        const unsigned short* __restrict__ atdR,
        int* __restrict__ flag, int* __restrict__ rowdeg, int* __restrict__ col,
        int* __restrict__ bucket, int use_bucket,
        unsigned short* __restrict__ canon,
        unsigned short* __restrict__ xp_all,
        float* __restrict__ as_all, float* __restrict__ ad_all,
        unsigned int* __restrict__ pooled) {
    const int t = threadIdx.x;
    const unsigned short* xs = (const unsigned short*)xraw;

    if (blockIdx.x < 8) {
        // ================= weight conversion (8-way split) =================
        __shared__ int dcnt;
        const int isf = detect_isf(xs, t, 256, &dcnt);
        if (blockIdx.x == 0 && t == 0) *flag = isf;
        const int gid = (int)blockIdx.x * 256 + t;         // 0..2047
        size_t base = 0;
        for (int s = 0; s < 10; ++s) {
            const int n = ca.n[s];
            if (isf) {
                const float* fp = (const float*)ca.src[s];
                for (int i = gid; i < n; i += 2048) canon[base + i] = f2bf(fp[i]);
            } else {
                const unsigned short* sp = ca.src[s];
                for (int i = gid; i < n; i += 2048) canon[base + i] = sp[i];
            }
            base += (size_t)n;
        }
    } else if (blockIdx.x == 8) {
        for (int i = t; i < kG * kHD; i += 256) pooled[i] = 0u;
    } else if (blockIdx.x < kSetupBlocks) {
        if (use_bucket) {
            // ============ parallel bucket scatter (32 blocks) ============
            const int gid = (int)(blockIdx.x - 9) * 256 + t;   // 0..8191
            const int* srcp = ei;
            const int* dstp = ei + kE;
            for (int e = gid; e < kE; e += 32 * 256) {
                const int d = dstp[e];
                const int pos = atomicAdd(&rowdeg[d], 1);
                if (pos < kBCAP) bucket[d * kBCAP + pos] = srcp[e];
            }
        } else if (blockIdx.x == 9) {
            // ============ serial CSR fallback (single block) ============
            __shared__ int cnt[1024];
            __shared__ int wtot[4];
            const int lane = t & 63, w = t >> 6;
            for (int i = t; i < 1024; i += 256) cnt[i] = 0;
            __syncthreads();
            const int* dst = ei + kE;
            for (int e = t; e < kE; e += 256) atomicAdd(&cnt[dst[e]], 1);
            __syncthreads();
            const int n0 = 4 * t;
            int c0 = cnt[n0], c1 = cnt[n0 + 1], c2 = cnt[n0 + 2], c3 = cnt[n0 + 3];
            int s0 = c0, s1 = s0 + c1, s2 = s1 + c2, s3 = s2 + c3;
            int tot = s3;
#pragma unroll
            for (int sft = 1; sft < 64; sft <<= 1) {
                int v = __shfl_up(tot, sft, 64);
                if (lane >= sft) tot += v;
            }
            if (lane == 63) wtot[w] = tot;
            __syncthreads();
            int wexcl = 0;
            for (int j = 0; j < w; ++j) wexcl += wtot[j];
            const int excl = wexcl + tot - s3;
            if (t == 0) rowdeg[0] = 0;
            if (n0 < kN) {
                rowdeg[n0 + 1] = excl + s0;
                rowdeg[n0 + 2] = excl + s1;
                rowdeg[n0 + 3] = excl + s2;
                rowdeg[n0 + 4] = excl + s3;
            }
            __syncthreads();
            cnt[n0] = excl; cnt[n0 + 1] = excl + s0;
            cnt[n0 + 2] = excl + s1; cnt[n0 + 3] = excl + s2;
            __syncthreads();
            for (int e = t; e < kE; e += 256) {
                int d0 = dst[e];
                int pos = atomicAdd(&cnt[d0], 1);
                col[pos] = ei[e];
            }
        }
    } else {
        // ================= wave-per-node precompute =================
        __shared__ int dcnt;
        const int isf = detect_isf(xs, t, 256, &dcnt);
        const int lane = t & 63;
        const int wv = t >> 6;
        const int wid = (int)(blockIdx.x - kSetupBlocks) * 4 + wv;  // 0..4095

        // per-lane weights: channel pair c0 = 2*lane, c0+1
        float wA[kF], wB[kF];
        float as0, as1, ad0, ad1;
        if (isf) {
            const float* wf = (const float*)WgR;
#pragma unroll
            for (int f = 0; f < kF; ++f) {
                const float2 wp = ((const float2*)(wf + (size_t)f * kHD))[lane];
                wA[f] = wp.x; wB[f] = wp.y;
            }
            const float2 sv = ((const float2*)atsR)[lane];
            as0 = sv.x; as1 = sv.y;
            const float2 dv2 = ((const float2*)atdR)[lane];
            ad0 = dv2.x; ad1 = dv2.y;
        } else {
            const uint32_t* w32 = (const uint32_t*)WgR;
#pragma unroll
            for (int f = 0; f < kF; ++f) {
                const uint32_t u = w32[f * 64 + lane];
                wA[f] = blo(u); wB[f] = bhi(u);
            }
            const uint32_t us = ((const uint32_t*)atsR)[lane];
            as0 = blo(us); as1 = bhi(us);
            const uint32_t ud = ((const uint32_t*)atdR)[lane];
            ad0 = blo(ud); ad1 = bhi(ud);
        }

        uint32_t* xp32 = (uint32_t*)xp_all;
        const int nEnd = min(wid * kNPW + kNPW, kG * kN);
        for (int node = wid * kNPW; node < nEnd; ++node) {
            float xv[kF];
            if (isf) {
                const float4* xr4 = (const float4*)((const float*)xraw + (size_t)node * kF);
                const float4 x0 = xr4[0], x1 = xr4[1], x2 = xr4[2], x3 = xr4[3];
                xv[0] = x0.x; xv[1] = x0.y; xv[2]  = x0.z; xv[3]  = x0.w;
                xv[4] = x1.x; xv[5] = x1.y; xv[6]  = x1.z; xv[7]  = x1.w;
                xv[8] = x2.x; xv[9] = x2.y; xv[10] = x2.z; xv[11] = x2.w;
                xv[12] = x3.x; xv[13] = x3.y; xv[14] = x3.z; xv[15] = x3.w;
            } else {
                const uint4* xr4 = (const uint4*)(xs + (size_t)node * kF);
                const uint4 q0 = xr4[0], q1 = xr4[1];
                xv[0]  = blo(q0.x); xv[1]  = bhi(q0.x);
                xv[2]  = blo(q0.y); xv[3]  = bhi(q0.y);
                xv[4]  = blo(q0.z); xv[5]  = bhi(q0.z);
                xv[6]  = blo(q0.w); xv[7]  = bhi(q0.w);
                xv[8]  = blo(q1.x); xv[9]  = bhi(q1.x);
                xv[10] = blo(q1.y); xv[11] = bhi(q1.y);
                xv[12] = blo(q1.z); xv[13] = bhi(q1.z);
                xv[14] = blo(q1.w); xv[15] = bhi(q1.w);
            }
            float vA = 0.f, vB = 0.f;
#pragma unroll
            for (int f = 0; f < kF; ++f) {
                vA = fmaf(xv[f], wA[f], vA);
                vB = fmaf(xv[f], wB[f], vB);
            }
            xp32[(size_t)node * 64 + lane] =
                (uint32_t)f2bf(vA) | ((uint32_t)f2bf(vB) << 16);
            // a_s/a_d: per-head (16-lane) butterfly reduce
            float aS = vA * as0 + vB * as1;
            float aD = vA * ad0 + vB * ad1;
#pragma unroll
            for (int sft = 1; sft < 16; sft <<= 1) {
                aS += __shfl_xor(aS, sft, 64);
                aD += __shfl_xor(aD, sft, 64);
            }
            if ((lane & 15) == 0) {
                as_all[(size_t)node * kH + (lane >> 4)] = aS;
                ad_all[(size_t)node * kH + (lane >> 4)] = aD;
            }
        }
    }
}

// ---------------------------------------------------------------------------
// Kernel 2: GAT edge-softmax aggregation + relu + max-pool.
// R2 operating point (3200 blocks, 40 nodes/block, 10 iters x 4 waves).
// R4: 2-deep gather MLP — full 8-edge pairs issue BOTH ds_read_b64 and BOTH
// 16-B gathers before consuming either (loads-in-flight 1 -> 2; attacks the
// exposed ~300-cyc chain that R3 showed is the stall: VALUBusy 68%, HBM 4%,
// conflicts negligible). Remainder (<8 edges) runs a single-gather tail so
// total gather count is unchanged (avoids R1's pad-to-8 overfetch).
// ---------------------------------------------------------------------------
__global__ __launch_bounds__(256) void gat_aggregate(
        const int* __restrict__ rowdeg, const int* __restrict__ col,
        const int* __restrict__ bucket, int use_bucket,
        const unsigned short* __restrict__ xp,
        const float* __restrict__ a_s, const float* __restrict__ a_d,
        const unsigned short* __restrict__ bg,
        unsigned int* __restrict__ pooled,
        float* __restrict__ part, int use_part) {
    __shared__ float2 colal[4][4][68];   // [wave][head][edge] {col_bits, alpha}
    __shared__ float pm[4][kHD];

    const int w = threadIdx.x >> 6;
    const int lane = threadIdx.x & 63;
    const int sub = lane >> 4;          // edge subgroup 0..3
    const int cl = lane & 15;           // channels cl*8 .. cl*8+7
    const int hh = cl >> 2;
    const int xcd = blockIdx.x & 7;
    const int j = blockIdx.x >> 3;      // 0..399
    const int gl = xcd + 8 * (j / kNB); // graph-major within XCD
    const int blk = j % kNB;            // 0..24
    const size_t gn = (size_t)gl * kN;
    const char* xpcl = (const char*)(xp + gn * kHD) + cl * 16;
    const float4* as4 = (const float4*)a_s + gn;
    const float4* ad4 = (const float4*)a_d + gn;
    const uint32_t* bg32 = (const uint32_t*)bg;
    float bgv[8];
#pragma unroll
    for (int jb = 0; jb < 4; ++jb) {
        uint32_t u = bg32[cl * 4 + jb];
        bgv[2 * jb] = blo(u);
        bgv[2 * jb + 1] = bhi(u);
    }
    float pool[8];
#pragma unroll
    for (int jb = 0; jb < 8; ++jb) pool[jb] = 0.f;

    for (int it = 0; it < 10; ++it) {
        const int n = blk * kNPB + it * 4 + w;
        int r0, deg;
        if (use_bucket) {
            r0 = n * kBCAP;
            deg = min(rowdeg[n], kBCAP);
        } else {
            r0 = rowdeg[n];
            deg = rowdeg[n + 1] - r0;
        }
        const int* colb = use_bucket ? bucket : col;
        const int E = deg + 1;          // + self loop (index deg)
        const float4 dv = ad4[n];
        v2f acc2[4];
#pragma unroll
        for (int jb = 0; jb < 4; ++jb) acc2[jb] = (v2f){0.f, 0.f};
        float dh = 0.f;

        for (int base = 0; base < E; base += 64) {
            const int cnt = min(64, E - base);
            const int cntP = (cnt + 3) & ~3;
            // ---- phase 1: lanes = edges (pad lanes get alpha 0) ----
            if (lane < cntP) {
                const int eg = base + lane;
                const bool act = lane < cnt;
                const int s = (act && eg < deg) ? colb[r0 + eg] : n;
                float p0 = 0.f, p1 = 0.f, p2 = 0.f, p3 = 0.f;
                if (act) {
                    const float4 av = as4[s];
                    float t0 = av.x + dv.x, t1 = av.y + dv.y;
                    float t2 = av.z + dv.z, t3 = av.w + dv.w;
                    t0 = t0 > 0.f ? t0 : kNeg * t0;
                    t1 = t1 > 0.f ? t1 : kNeg * t1;
                    t2 = t2 > 0.f ? t2 : kNeg * t2;
                    t3 = t3 > 0.f ? t3 : kNeg * t3;
                    p0 = __expf(t0); p1 = __expf(t1);
                    p2 = __expf(t2); p3 = __expf(t3);
                }
                const float cf = __int_as_float(s << 8);   // xp row byte offset
                colal[w][0][lane] = make_float2(cf, p0);
                colal[w][1][lane] = make_float2(cf, p1);
                colal[w][2][lane] = make_float2(cf, p2);
                colal[w][3][lane] = make_float2(cf, p3);
            }
            // wave-synchronous LDS use; 2-deep paired gathers for full 8-groups
            int e0 = 0;
            for (; e0 + 8 <= cntP; e0 += 8) {
                const float2 cA = colal[w][hh][e0 + sub];
                const float2 cB = colal[w][hh][e0 + 4 + sub];
                const uint4 uA = *(const uint4*)(xpcl + __float_as_int(cA.x));
                const uint4 uB = *(const uint4*)(xpcl + __float_as_int(cB.x));
                const float aA = cA.y, aB = cB.y;
                const v2f aA2 = {aA, aA}, aB2 = {aB, aB};
                acc2[0] += aA2 * (v2f){blo(uA.x), bhi(uA.x)};
                acc2[1] += aA2 * (v2f){blo(uA.y), bhi(uA.y)};
                acc2[2] += aA2 * (v2f){blo(uA.z), bhi(uA.z)};
                acc2[3] += aA2 * (v2f){blo(uA.w), bhi(uA.w)};
                acc2[0] += aB2 * (v2f){blo(uB.x), bhi(uB.x)};
                acc2[1] += aB2 * (v2f){blo(uB.y), bhi(uB.y)};
                acc2[2] += aB2 * (v2f){blo(uB.z), bhi(uB.z)};
                acc2[3] += aB2 * (v2f){blo(uB.w), bhi(uB.w)};
                dh += aA + aB;
            }
            if (e0 < cntP) {
                const float2 cA = colal[w][hh][e0 + sub];
                const uint4 uA = *(const uint4*)(xpcl + __float_as_int(cA.x));
                const float aA = cA.y;
                const v2f aA2 = {aA, aA};
                acc2[0] += aA2 * (v2f){blo(uA.x), bhi(uA.x)};
                acc2[1] += aA2 * (v2f){blo(uA.y), bhi(uA.y)};
                acc2[2] += aA2 * (v2f){blo(uA.z), bhi(uA.z)};
                acc2[3] += aA2 * (v2f){blo(uA.w), bhi(uA.w)};
                dh += aA;
            }
        }
        float acc[8];
#pragma unroll
        for (int jb = 0; jb < 4; ++jb) {
            acc[2 * jb] = acc2[jb].x;
            acc[2 * jb + 1] = acc2[jb].y;
        }
#pragma unroll
        for (int jb = 0; jb < 8; ++jb) {
            acc[jb] += __shfl_xor(acc[jb], 16, 64);
            acc[jb] += __shfl_xor(acc[jb], 32, 64);
        }
        dh += __shfl_xor(dh, 16, 64);
        dh += __shfl_xor(dh, 32, 64);
        const float inv = 1.f / dh;
#pragma unroll
        for (int jb = 0; jb < 8; ++jb) {
            const float o = acc[jb] * inv + bgv[jb];
            pool[jb] = fmaxf(pool[jb], o > 0.f ? o : 0.f);
        }
    }
    if (sub == 0) {
#pragma unroll
        for (int jb = 0; jb < 8; ++jb) pm[w][cl * 8 + jb] = pool[jb];
    }
    __syncthreads();
    if (w == 0 && sub == 0) {
        if (use_part) {
            float* dst = part + ((size_t)gl * kNB + blk) * kHD;
#pragma unroll
            for (int jb = 0; jb < 8; ++jb) {
                const int c = cl * 8 + jb;
                dst[c] = fmaxf(fmaxf(pm[0][c], pm[1][c]), fmaxf(pm[2][c], pm[3][c]));
            }
        } else {
            const size_t gp = (size_t)gl * kHD;
#pragma unroll
            for (int jb = 0; jb < 8; ++jb) {
                const int c = cl * 8 + jb;
                float vmax = fmaxf(fmaxf(pm[0][c], pm[1][c]), fmaxf(pm[2][c], pm[3][c]));
                atomicMax(pooled + gp + c, __float_as_uint(vmax));
            }
        }
    }
}

// ---------------------------------------------------------------------------
// Kernel 3: LSTM over T=16 + classifier. One block per batch row b.
// xt load folds the kNB-way partial-max reduce when use_part=1.
// ---------------------------------------------------------------------------
__global__ __launch_bounds__(256) void lstm_head(
        const float* __restrict__ pooled, const float* __restrict__ part,
        int use_part,
        const unsigned short* __restrict__ Wih,
        const unsigned short* __restrict__ Whh,
        const unsigned short* __restrict__ bih,
        const unsigned short* __restrict__ bhh,
        const unsigned short* __restrict__ Wclf,
        const unsigned short* __restrict__ bclf,
        const int* __restrict__ flag,
        void* __restrict__ out) {
    const int b = blockIdx.x;
    const int r = threadIdx.x;
    __shared__ float xt[kHD];
    __shared__ float hs[kHL];
    __shared__ float gates[4 * kHL];

    uint32_t wih[64];
    const uint32_t* pw = (const uint32_t*)(Wih + (size_t)r * kHD);
#pragma unroll
    for (int j = 0; j < 64; ++j) wih[j] = pw[j];
    uint32_t whh[32];
    const uint32_t* ph = (const uint32_t*)(Whh + (size_t)r * kHL);
#pragma unroll
    for (int j = 0; j < 32; ++j) whh[j] = ph[j];
    const float bias = bf2f(bih[r]) + bf2f(bhh[r]);

    float c_st = 0.f;
    if (r < kHL) hs[r] = 0.f;
    __syncthreads();

    for (int t = 0; t < kT; ++t) {
        const size_t g = (size_t)b * kT + t;
        if (r < kHD) {
            if (use_part) {
                const float* ps = part + g * kNB * kHD + r;
                float v = ps[0];
#pragma unroll
                for (int k = 1; k < kNB; ++k) v = fmaxf(v, ps[(size_t)k * kHD]);
                xt[r] = v;
            } else {
                xt[r] = pooled[g * kHD + r];
            }
        }
        __syncthreads();
        float a0 = 0.f, a1 = 0.f, a2 = 0.f, a3 = 0.f;
#pragma unroll
        for (int j = 0; j < 64; j += 4) {
            uint32_t u0 = wih[j], u1 = wih[j + 1], u2 = wih[j + 2], u3 = wih[j + 3];
            a0 += blo(u0) * xt[2 * j + 0] + bhi(u0) * xt[2 * j + 1];
            a1 += blo(u1) * xt[2 * j + 2] + bhi(u1) * xt[2 * j + 3];
            a2 += blo(u2) * xt[2 * j + 4] + bhi(u2) * xt[2 * j + 5];
            a3 += blo(u3) * xt[2 * j + 6] + bhi(u3) * xt[2 * j + 7];
        }
#pragma unroll
        for (int j = 0; j < 32; j += 4) {
            uint32_t u0 = whh[j], u1 = whh[j + 1], u2 = whh[j + 2], u3 = whh[j + 3];
            a0 += blo(u0) * hs[2 * j + 0] + bhi(u0) * hs[2 * j + 1];
            a1 += blo(u1) * hs[2 * j + 2] + bhi(u1) * hs[2 * j + 3];
            a2 += blo(u2) * hs[2 * j + 4] + bhi(u2) * hs[2 * j + 5];
            a3 += blo(u3) * hs[2 * j + 6] + bhi(u3) * hs[2 * j + 7];
        }
        gates[r] = bias + (a0 + a1) + (a2 + a3);
        __syncthreads();
        if (r < kHL) {
            const float iv = sigm(gates[r]);
            const float fv = sigm(gates[kHL + r]);
            const float gv = tanhf(gates[2 * kHL + r]);
            const float ov = sigm(gates[3 * kHL + r]);
            c_st = fv * c_st + iv * gv;
            hs[r] = ov * tanhf(c_st);
        }
        __syncthreads();
    }
    if (r < kOUT) {
        float acc = bf2f(bclf[r]);
#pragma unroll
        for (int k = 0; k < kHL; ++k) acc += hs[k] * bf2f(Wclf[r * kHL + k]);
        if (*flag) ((float*)out)[b * kOUT + r] = acc;
        else ((__hip_bfloat16*)out)[b * kOUT + r] = __float2bfloat16(acc);
    }
}

// ---------------------------------------------------------------------------
extern "C" void kernel_launch(void* const* d_in, const int* in_sizes, int n_in,
                              void* d_out, int out_size, void* d_ws, size_t ws_size,
                              hipStream_t stream) {
    const int* ei = (const int*)d_in[1];

    char* ws = (char*)d_ws;
    int*            flag   = (int*)(ws + OFF_FLAG);
    int*            rowdeg = (int*)(ws + OFF_ROW);
    int*            colv   = (int*)(ws + OFF_COL);
    unsigned int*   pooled = (unsigned int*)(ws + OFF_POOL);
    unsigned short* canon  = (unsigned short*)(ws + OFF_CANON);

    unsigned short* cBg   = canon + CX_BG;
    unsigned short* cWih  = canon + CX_WIH;
    unsigned short* cWhh  = canon + CX_WHH;
    unsigned short* cBih  = canon + CX_BIH;
    unsigned short* cBhh  = canon + CX_BHH;
    unsigned short* cWclf = canon + CX_WCLF;
    unsigned short* cBclf = canon + CX_BCLF;

    float*          a_s = (float*)(ws + OFF_AS);
    float*          a_d = (float*)(ws + OFF_AS + (size_t)kG * 16000);
    unsigned short* xp  = (unsigned short*)(ws + OFF_AS + (size_t)kG * 32000);

    // ws_size is fixed per session -> flags constant -> graph-capture safe
    const int use_part   = (ws_size >= OFF_PPART + PPART_BYTES) ? 1 : 0;
    const int use_bucket = (ws_size >= OFF_BUCKET + BUCKET_BYTES) ? 1 : 0;
    float* part   = (float*)(ws + OFF_PPART);
    int*   bucket = (int*)(ws + OFF_BUCKET);

    ConvArgs ca;
    const int sizes[10] = {2048, 128, 128, 128, 32768, 16384, 256, 256, 512, 8};
    const int which[10] = {2, 3, 4, 5, 6, 7, 8, 9, 10, 11};
    for (int i = 0; i < 10; ++i) {
        ca.src[i] = (const unsigned short*)d_in[which[i]];
        ca.n[i] = sizes[i];
    }

    // zero deg (bucket path) — 4 KB, graph-capture-safe memset node
    hipMemsetAsync(ws + OFF_ROW, 0, 4096, stream);

    mega_setup<<<kSetupBlocks + kPre, 256, 0, stream>>>(
        d_in[0], ei, ca,
        (const unsigned short*)d_in[2], (const unsigned short*)d_in[3],
        (const unsigned short*)d_in[4],
        flag, rowdeg, colv, bucket, use_bucket, canon, xp, a_s, a_d, pooled);
    gat_aggregate<<<kG * kNB, 256, 0, stream>>>(rowdeg, colv, bucket, use_bucket,
                                                xp, a_s, a_d, cBg,
                                                pooled, part, use_part);
    lstm_head<<<kB, 256, 0, stream>>>((const float*)pooled, part, use_part,
                                      cWih, cWhh, cBih, cBhh,
                                      cWclf, cBclf, flag, d_out);
}

// Round 5
// 199.875 us; speedup vs baseline: 1.0337x; 1.0035x over previous
//
#include <hip/hip_runtime.h>
#include <hip/hip_bf16.h>
#include <stdint.h>

namespace {
constexpr int kB = 8, kT = 16, kN = 1000, kF = 16;
constexpr int kE = 16000;
constexpr int kH = 4, kHD = 128;
constexpr int kHL = 64, kOUT = 8;
constexpr int kG = kB * kT;
constexpr float kNeg = 0.2f;
constexpr int kNB = 25;                  // gat blocks per graph (R0/R2 operating point)
constexpr int kNPB = 40;                 // nodes per gat block
constexpr int kPre = 1024;               // precompute blocks (R2 config)
constexpr int kNPW = 32;                 // nodes per precompute wave (R2 config)
constexpr int kBCAP = 64;                // bucket capacity per node (Poisson(16) tail ~1e-18)

// Canonical bf16 weights (for lstm_head + bg), element offsets:
constexpr size_t CX_WG   = 0;                       // 2048 (layout only)
constexpr size_t CX_ATS  = CX_WG   + 2048;
constexpr size_t CX_ATD  = CX_ATS  + 128;
constexpr size_t CX_BG   = CX_ATD  + 128;
constexpr size_t CX_WIH  = CX_BG   + 128;
constexpr size_t CX_WHH  = CX_WIH  + 32768;
constexpr size_t CX_BIH  = CX_WHH  + 16384;
constexpr size_t CX_BHH  = CX_BIH  + 256;
constexpr size_t CX_WCLF = CX_BHH  + 256;
constexpr size_t CX_BCLF = CX_WCLF + 512;
constexpr size_t CX_TOTAL = CX_BCLF + 8;

// Workspace byte offsets (256-aligned)
constexpr size_t OFF_FLAG  = 0;
constexpr size_t OFF_ROW   = 256;                    // deg[1000] (bucket) | row[1001] (fallback)
constexpr size_t OFF_COL   = 4352;                   // col[16000] (fallback only)
constexpr size_t OFF_POOL  = 68608;                  // float[kG*kHD] (atomic fallback)
constexpr size_t OFF_CANON = 134400;                 // bf16[CX_TOTAL]
constexpr size_t OFF_AS    = 239872;
// a_s: 128*16000 B, a_d: 128*16000 B, xp(bf16): 128*256000 B
constexpr size_t OFF_PPART = OFF_AS + (size_t)kG * 288000;     // 37,103,872
constexpr size_t PPART_BYTES = (size_t)kG * kNB * kHD * 4;     // 1,638,400
constexpr size_t OFF_BUCKET = OFF_PPART + PPART_BYTES;         // 38,742,272
constexpr size_t BUCKET_BYTES = (size_t)kN * kBCAP * 4;        // 256,000

constexpr int kSetupBlocks = 41;   // 0-7 convert, 8 zero-pool, 9-40 scatter (or 9=serial CSR)
}

typedef float v2f __attribute__((ext_vector_type(2)));

__device__ __forceinline__ float bf2f(unsigned short u) {
    return __uint_as_float(((uint32_t)u) << 16);
}
__device__ __forceinline__ float blo(uint32_t u) { return __uint_as_float(u << 16); }
__device__ __forceinline__ float bhi(uint32_t u) { return __uint_as_float(u & 0xffff0000u); }
__device__ __forceinline__ unsigned short f2bf(float f) {
    uint32_t u = __float_as_uint(f);
    uint32_t r = (u + 0x7fff + ((u >> 16) & 1)) >> 16;
    return (unsigned short)r;
}
__device__ __forceinline__ float sigm(float x) { return 1.f / (1.f + __expf(-x)); }

// dtype probe: bf16 N(0,1) shorts are ~100% in exponent band [97,143];
// fp32 viewed as shorts ~55-59%. 512 samples is plenty of separation.
__device__ __forceinline__ int detect_isf(const unsigned short* xs, int t,
                                          int nthr, int* sh_cnt) {
    if (t == 0) *sh_cnt = 0;
    __syncthreads();
    int loc = 0;
    for (int i = t; i < 512; i += nthr) {
        unsigned short u = xs[i];
        int ex = (u >> 7) & 0xff;
        if (u == 0 || (ex >= 97 && ex <= 143)) loc++;
    }
    atomicAdd(sh_cnt, loc);
    __syncthreads();
    return (*sh_cnt >= 410) ? 0 : 1;
}

struct ConvArgs {
    const unsigned short* src[10];
    int n[10];
};

// ---------------------------------------------------------------------------
// Kernel 1 (mega-setup, 41+1024 blocks x 256 — R2 configuration):
//  blocks 0-7:  convert weights to canonical bf16 (8-way split)
//  block 8:     zero pooled (atomic fallback only)
//  blocks 9-40: PARALLEL edge scatter into fixed-cap buckets (deg via global
//               atomicAdd; deg pre-zeroed by hipMemsetAsync).
//               Fallback (!use_bucket): block 9 runs the old serial CSR.
//  blocks 41+:  wave-per-node precompute (W_gat in 32 VGPRs/lane, xp packed
//               stores, a_s/a_d via 16-lane shfl_xor butterfly; no LDS).
// ---------------------------------------------------------------------------
__global__ __launch_bounds__(256) void mega_setup(
        const void* __restrict__ xraw, const int* __restrict__ ei,
        ConvArgs ca,
        const unsigned short* __restrict__ WgR,
        const unsigned short* __restrict__ atsR,
        const unsigned short* __restrict__ atdR,
        int* __restrict__ flag, int* __restrict__ rowdeg, int* __restrict__ col,
        int* __restrict__ bucket, int use_bucket,
        unsigned short* __restrict__ canon,
        unsigned short* __restrict__ xp_all,
        float* __restrict__ as_all, float* __restrict__ ad_all,
        unsigned int* __restrict__ pooled) {
    const int t = threadIdx.x;
    const unsigned short* xs = (const unsigned short*)xraw;

    if (blockIdx.x < 8) {
        // ================= weight conversion (8-way split) =================
        __shared__ int dcnt;
        const int isf = detect_isf(xs, t, 256, &dcnt);
        if (blockIdx.x == 0 && t == 0) *flag = isf;
        const int gid = (int)blockIdx.x * 256 + t;         // 0..2047
        size_t base = 0;
        for (int s = 0; s < 10; ++s) {
            const int n = ca.n[s];
            if (isf) {
                const float* fp = (const float*)ca.src[s];
                for (int i = gid; i < n; i += 2048) canon[base + i] = f2bf(fp[i]);
            } else {
                const unsigned short* sp = ca.src[s];
                for (int i = gid; i < n; i += 2048) canon[base + i] = sp[i];
            }
            base += (size_t)n;
        }
    } else if (blockIdx.x == 8) {
        for (int i = t; i < kG * kHD; i += 256) pooled[i] = 0u;
    } else if (blockIdx.x < kSetupBlocks) {
        if (use_bucket) {
            // ============ parallel bucket scatter (32 blocks) ============
            const int gid = (int)(blockIdx.x - 9) * 256 + t;   // 0..8191
            const int* srcp = ei;
            const int* dstp = ei + kE;
            for (int e = gid; e < kE; e += 32 * 256) {
                const int d = dstp[e];
                const int pos = atomicAdd(&rowdeg[d], 1);
                if (pos < kBCAP) bucket[d * kBCAP + pos] = srcp[e];
            }
        } else if (blockIdx.x == 9) {
            // ============ serial CSR fallback (single block) ============
            __shared__ int cnt[1024];
            __shared__ int wtot[4];
            const int lane = t & 63, w = t >> 6;
            for (int i = t; i < 1024; i += 256) cnt[i] = 0;
            __syncthreads();
            const int* dst = ei + kE;
            for (int e = t; e < kE; e += 256) atomicAdd(&cnt[dst[e]], 1);
            __syncthreads();
            const int n0 = 4 * t;
            int c0 = cnt[n0], c1 = cnt[n0 + 1], c2 = cnt[n0 + 2], c3 = cnt[n0 + 3];
            int s0 = c0, s1 = s0 + c1, s2 = s1 + c2, s3 = s2 + c3;
            int tot = s3;
#pragma unroll
            for (int sft = 1; sft < 64; sft <<= 1) {
                int v = __shfl_up(tot, sft, 64);
                if (lane >= sft) tot += v;
            }
            if (lane == 63) wtot[w] = tot;
            __syncthreads();
            int wexcl = 0;
            for (int j = 0; j < w; ++j) wexcl += wtot[j];
            const int excl = wexcl + tot - s3;
            if (t == 0) rowdeg[0] = 0;
            if (n0 < kN) {
                rowdeg[n0 + 1] = excl + s0;
                rowdeg[n0 + 2] = excl + s1;
                rowdeg[n0 + 3] = excl + s2;
                rowdeg[n0 + 4] = excl + s3;
            }
            __syncthreads();
            cnt[n0] = excl; cnt[n0 + 1] = excl + s0;
            cnt[n0 + 2] = excl + s1; cnt[n0 + 3] = excl + s2;
            __syncthreads();
            for (int e = t; e < kE; e += 256) {
                int d0 = dst[e];
                int pos = atomicAdd(&cnt[d0], 1);
                col[pos] = ei[e];
            }
        }
    } else {
        // ================= wave-per-node precompute =================
        __shared__ int dcnt;
        const int isf = detect_isf(xs, t, 256, &dcnt);
        const int lane = t & 63;
        const int wv = t >> 6;
        const int wid = (int)(blockIdx.x - kSetupBlocks) * 4 + wv;  // 0..4095

        // per-lane weights: channel pair c0 = 2*lane, c0+1
        float wA[kF], wB[kF];
        float as0, as1, ad0, ad1;
        if (isf) {
            const float* wf = (const float*)WgR;
#pragma unroll
            for (int f = 0; f < kF; ++f) {
                const float2 wp = ((const float2*)(wf + (size_t)f * kHD))[lane];
                wA[f] = wp.x; wB[f] = wp.y;
            }
            const float2 sv = ((const float2*)atsR)[lane];
            as0 = sv.x; as1 = sv.y;
            const float2 dv2 = ((const float2*)atdR)[lane];
            ad0 = dv2.x; ad1 = dv2.y;
        } else {
            const uint32_t* w32 = (const uint32_t*)WgR;
#pragma unroll
            for (int f = 0; f < kF; ++f) {
                const uint32_t u = w32[f * 64 + lane];
                wA[f] = blo(u); wB[f] = bhi(u);
            }
            const uint32_t us = ((const uint32_t*)atsR)[lane];
            as0 = blo(us); as1 = bhi(us);
            const uint32_t ud = ((const uint32_t*)atdR)[lane];
            ad0 = blo(ud); ad1 = bhi(ud);
        }

        uint32_t* xp32 = (uint32_t*)xp_all;
        const int nEnd = min(wid * kNPW + kNPW, kG * kN);
        for (int node = wid * kNPW; node < nEnd; ++node) {
            float xv[kF];
            if (isf) {
                const float4* xr4 = (const float4*)((const float*)xraw + (size_t)node * kF);
                const float4 x0 = xr4[0], x1 = xr4[1], x2 = xr4[2], x3 = xr4[3];
                xv[0] = x0.x; xv[1] = x0.y; xv[2]  = x0.z; xv[3]  = x0.w;
                xv[4] = x1.x; xv[5] = x1.y; xv[6]  = x1.z; xv[7]  = x1.w;
                xv[8] = x2.x; xv[9] = x2.y; xv[10] = x2.z; xv[11] = x2.w;
                xv[12] = x3.x; xv[13] = x3.y; xv[14] = x3.z; xv[15] = x3.w;
            } else {
                const uint4* xr4 = (const uint4*)(xs + (size_t)node * kF);
                const uint4 q0 = xr4[0], q1 = xr4[1];
                xv[0]  = blo(q0.x); xv[1]  = bhi(q0.x);
                xv[2]  = blo(q0.y); xv[3]  = bhi(q0.y);
                xv[4]  = blo(q0.z); xv[5]  = bhi(q0.z);
                xv[6]  = blo(q0.w); xv[7]  = bhi(q0.w);
                xv[8]  = blo(q1.x); xv[9]  = bhi(q1.x);
                xv[10] = blo(q1.y); xv[11] = bhi(q1.y);
                xv[12] = blo(q1.z); xv[13] = bhi(q1.z);
                xv[14] = blo(q1.w); xv[15] = bhi(q1.w);
            }
            float vA = 0.f, vB = 0.f;
#pragma unroll
            for (int f = 0; f < kF; ++f) {
                vA = fmaf(xv[f], wA[f], vA);
                vB = fmaf(xv[f], wB[f], vB);
            }
            xp32[(size_t)node * 64 + lane] =
                (uint32_t)f2bf(vA) | ((uint32_t)f2bf(vB) << 16);
            // a_s/a_d: per-head (16-lane) butterfly reduce
            float aS = vA * as0 + vB * as1;
            float aD = vA * ad0 + vB * ad1;
#pragma unroll
            for (int sft = 1; sft < 16; sft <<= 1) {
                aS += __shfl_xor(aS, sft, 64);
                aD += __shfl_xor(aD, sft, 64);
            }
            if ((lane & 15) == 0) {
                as_all[(size_t)node * kH + (lane >> 4)] = aS;
                ad_all[(size_t)node * kH + (lane >> 4)] = aD;
            }
        }
    }
}

// ---------------------------------------------------------------------------
// Kernel 2: GAT edge-softmax aggregation + relu + max-pool.
// R2 operating point (3200 blocks, 40 nodes/block, 10 iters x 4 waves).
// R5: cross-node software pipeline (bucket path). R4 evidence: per-wave time
// ~13K cycles vs ~2K of issue -> 85% stall, dominated by the per-node serial
// chain {col load -> dependent as4 gather -> exp -> inner}. Since deg<=63
// (bucket cap), each node is ONE chunk, so while node n computes we prefetch
// node n+1's meta+col (at iteration top) and issue its as4 gather after the
// first inner 8-group (~200cy in, col returned). Both L2 round trips hide
// under current-node compute.
// ---------------------------------------------------------------------------
__global__ __launch_bounds__(256) void gat_aggregate(
        const int* __restrict__ rowdeg, const int* __restrict__ col,
        const int* __restrict__ bucket, int use_bucket,
        const unsigned short* __restrict__ xp,
        const float* __restrict__ a_s, const float* __restrict__ a_d,
        const unsigned short* __restrict__ bg,
        unsigned int* __restrict__ pooled,
        float* __restrict__ part, int use_part) {
    __shared__ float2 colal[4][4][68];   // [wave][head][edge] {col_bits, alpha}
    __shared__ float pm[4][kHD];

    const int w = threadIdx.x >> 6;
    const int lane = threadIdx.x & 63;
    const int sub = lane >> 4;          // edge subgroup 0..3
    const int cl = lane & 15;           // channels cl*8 .. cl*8+7
    const int hh = cl >> 2;
    const int xcd = blockIdx.x & 7;
    const int j = blockIdx.x >> 3;      // 0..399
    const int gl = xcd + 8 * (j / kNB); // graph-major within XCD
    const int blk = j % kNB;            // 0..24
    const size_t gn = (size_t)gl * kN;
    const char* xpcl = (const char*)(xp + gn * kHD) + cl * 16;
    const float4* as4 = (const float4*)a_s + gn;
    const float4* ad4 = (const float4*)a_d + gn;
    const uint32_t* bg32 = (const uint32_t*)bg;
    float bgv[8];
#pragma unroll
    for (int jb = 0; jb < 4; ++jb) {
        uint32_t u = bg32[cl * 4 + jb];
        bgv[2 * jb] = blo(u);
        bgv[2 * jb + 1] = bhi(u);
    }
    float pool[8];
#pragma unroll
    for (int jb = 0; jb < 8; ++jb) pool[jb] = 0.f;

    auto pairBody = [&](v2f* acc2, float& dh, int e0) {
        const float2 cA = colal[w][hh][e0 + sub];
        const float2 cB = colal[w][hh][e0 + 4 + sub];
        const uint4 uA = *(const uint4*)(xpcl + __float_as_int(cA.x));
        const uint4 uB = *(const uint4*)(xpcl + __float_as_int(cB.x));
        const float aA = cA.y, aB = cB.y;
        const v2f aA2 = {aA, aA}, aB2 = {aB, aB};
        acc2[0] += aA2 * (v2f){blo(uA.x), bhi(uA.x)};
        acc2[1] += aA2 * (v2f){blo(uA.y), bhi(uA.y)};
        acc2[2] += aA2 * (v2f){blo(uA.z), bhi(uA.z)};
        acc2[3] += aA2 * (v2f){blo(uA.w), bhi(uA.w)};
        acc2[0] += aB2 * (v2f){blo(uB.x), bhi(uB.x)};
        acc2[1] += aB2 * (v2f){blo(uB.y), bhi(uB.y)};
        acc2[2] += aB2 * (v2f){blo(uB.z), bhi(uB.z)};
        acc2[3] += aB2 * (v2f){blo(uB.w), bhi(uB.w)};
        dh += aA + aB;
    };
    auto singleBody = [&](v2f* acc2, float& dh, int e0) {
        const float2 cA = colal[w][hh][e0 + sub];
        const uint4 uA = *(const uint4*)(xpcl + __float_as_int(cA.x));
        const float aA = cA.y;
        const v2f aA2 = {aA, aA};
        acc2[0] += aA2 * (v2f){blo(uA.x), bhi(uA.x)};
        acc2[1] += aA2 * (v2f){blo(uA.y), bhi(uA.y)};
        acc2[2] += aA2 * (v2f){blo(uA.z), bhi(uA.z)};
        acc2[3] += aA2 * (v2f){blo(uA.w), bhi(uA.w)};
        dh += aA;
    };
    auto finishNode = [&](v2f* acc2, float dh) {
        float acc[8];
#pragma unroll
        for (int jb = 0; jb < 4; ++jb) {
            acc[2 * jb] = acc2[jb].x;
            acc[2 * jb + 1] = acc2[jb].y;
        }
#pragma unroll
        for (int jb = 0; jb < 8; ++jb) {
            acc[jb] += __shfl_xor(acc[jb], 16, 64);
            acc[jb] += __shfl_xor(acc[jb], 32, 64);
        }
        dh += __shfl_xor(dh, 16, 64);
        dh += __shfl_xor(dh, 32, 64);
        const float inv = 1.f / dh;
#pragma unroll
        for (int jb = 0; jb < 8; ++jb) {
            const float o = acc[jb] * inv + bgv[jb];
            pool[jb] = fmaxf(pool[jb], o > 0.f ? o : 0.f);
        }
    };

    if (use_bucket) {
        // ======= software-pipelined single-chunk path (E <= 64) =======
        // prologue: node for it=0
        int nidx = blk * kNPB + w;
        int degc = min(rowdeg[nidx], 63);
        int sc = (lane < degc) ? bucket[nidx * kBCAP + lane] : nidx;
        float4 avc = as4[sc];
        float4 dvc = ad4[nidx];

        for (int it = 0; it < 10; ++it) {
            const int deg = degc;
            const int E = deg + 1;
            const int cntP = (E + 3) & ~3;
            const int s = sc;
            const float4 av = avc;
            const float4 dv = dvc;

            // ---- phase 1: exp + LDS (lanes < cntP) ----
            if (lane < cntP) {
                float p0 = 0.f, p1 = 0.f, p2 = 0.f, p3 = 0.f;
                if (lane < E) {
                    float t0 = av.x + dv.x, t1 = av.y + dv.y;
                    float t2 = av.z + dv.z, t3 = av.w + dv.w;
                    t0 = t0 > 0.f ? t0 : kNeg * t0;
                    t1 = t1 > 0.f ? t1 : kNeg * t1;
                    t2 = t2 > 0.f ? t2 : kNeg * t2;
                    t3 = t3 > 0.f ? t3 : kNeg * t3;
                    p0 = __expf(t0); p1 = __expf(t1);
                    p2 = __expf(t2); p3 = __expf(t3);
                }
                const float cf = __int_as_float(s << 8);   // xp row byte offset
                colal[w][0][lane] = make_float2(cf, p0);
                colal[w][1][lane] = make_float2(cf, p1);
                colal[w][2][lane] = make_float2(cf, p2);
                colal[w][3][lane] = make_float2(cf, p3);
            }

            // ---- prefetch next node: meta + col + dv (independent loads) ----
            const int itn = (it + 1 == 10) ? 0 : (it + 1);   // wrap: last-iter
            const int n_nxt = blk * kNPB + itn * 4 + w;      //  prefetch harmless
            degc = min(rowdeg[n_nxt], 63);
            dvc = ad4[n_nxt];
            sc = (lane < degc) ? bucket[n_nxt * kBCAP + lane] : n_nxt;
            nidx = n_nxt;

            // ---- inner: first 8-group, then issue next as4 gather, then rest
            v2f acc2[4];
#pragma unroll
            for (int jb = 0; jb < 4; ++jb) acc2[jb] = (v2f){0.f, 0.f};
            float dh = 0.f;
            int e0 = 0;
            if (cntP >= 8) { pairBody(acc2, dh, 0); e0 = 8; }
            avc = as4[sc];                 // col' returned by now; hide under rest
            for (; e0 + 8 <= cntP; e0 += 8) pairBody(acc2, dh, e0);
            if (e0 < cntP) singleBody(acc2, dh, e0);

            finishNode(acc2, dh);
        }
    } else {
        // ======= fallback: CSR chunked path (unchanged R4 structure) =======
        for (int it = 0; it < 10; ++it) {
            const int n = blk * kNPB + it * 4 + w;
            const int r0 = rowdeg[n];
            const int deg = rowdeg[n + 1] - r0;
            const int E = deg + 1;
            const float4 dv = ad4[n];
            v2f acc2[4];
#pragma unroll
            for (int jb = 0; jb < 4; ++jb) acc2[jb] = (v2f){0.f, 0.f};
            float dh = 0.f;

            for (int base = 0; base < E; base += 64) {
                const int cnt = min(64, E - base);
                const int cntP = (cnt + 3) & ~3;
                if (lane < cntP) {
                    const int eg = base + lane;
                    const bool act = lane < cnt;
                    const int s = (act && eg < deg) ? col[r0 + eg] : n;
                    float p0 = 0.f, p1 = 0.f, p2 = 0.f, p3 = 0.f;
                    if (act) {
                        const float4 av = as4[s];
                        float t0 = av.x + dv.x, t1 = av.y + dv.y;
                        float t2 = av.z + dv.z, t3 = av.w + dv.w;
                        t0 = t0 > 0.f ? t0 : kNeg * t0;
                        t1 = t1 > 0.f ? t1 : kNeg * t1;
                        t2 = t2 > 0.f ? t2 : kNeg * t2;
                        t3 = t3 > 0.f ? t3 : kNeg * t3;
                        p0 = __expf(t0); p1 = __expf(t1);
                        p2 = __expf(t2); p3 = __expf(t3);
                    }
                    const float cf = __int_as_float(s << 8);
                    colal[w][0][lane] = make_float2(cf, p0);
                    colal[w][1][lane] = make_float2(cf, p1);
                    colal[w][2][lane] = make_float2(cf, p2);
                    colal[w][3][lane] = make_float2(cf, p3);
                }
                int e0 = 0;
                for (; e0 + 8 <= cntP; e0 += 8) pairBody(acc2, dh, e0);
                if (e0 < cntP) singleBody(acc2, dh, e0);
            }
            finishNode(acc2, dh);
        }
    }

    if (sub == 0) {
#pragma unroll
        for (int jb = 0; jb < 8; ++jb) pm[w][cl * 8 + jb] = pool[jb];
    }
    __syncthreads();
    if (w == 0 && sub == 0) {
        if (use_part) {
            float* dst = part + ((size_t)gl * kNB + blk) * kHD;
#pragma unroll
            for (int jb = 0; jb < 8; ++jb) {
                const int c = cl * 8 + jb;
                dst[c] = fmaxf(fmaxf(pm[0][c], pm[1][c]), fmaxf(pm[2][c], pm[3][c]));
            }
        } else {
            const size_t gp = (size_t)gl * kHD;
#pragma unroll
            for (int jb = 0; jb < 8; ++jb) {
                const int c = cl * 8 + jb;
                float vmax = fmaxf(fmaxf(pm[0][c], pm[1][c]), fmaxf(pm[2][c], pm[3][c]));
                atomicMax(pooled + gp + c, __float_as_uint(vmax));
            }
        }
    }
}

// ---------------------------------------------------------------------------
// Kernel 3: LSTM over T=16 + classifier. One block per batch row b.
// xt load folds the kNB-way partial-max reduce when use_part=1.
// ---------------------------------------------------------------------------
__global__ __launch_bounds__(256) void lstm_head(
        const float* __restrict__ pooled, const float* __restrict__ part,
        int use_part,
        const unsigned short* __restrict__ Wih,
        const unsigned short* __restrict__ Whh,
        const unsigned short* __restrict__ bih,
        const unsigned short* __restrict__ bhh,
        const unsigned short* __restrict__ Wclf,
        const unsigned short* __restrict__ bclf,
        const int* __restrict__ flag,
        void* __restrict__ out) {
    const int b = blockIdx.x;
    const int r = threadIdx.x;
    __shared__ float xt[kHD];
    __shared__ float hs[kHL];
    __shared__ float gates[4 * kHL];

    uint32_t wih[64];
    const uint32_t* pw = (const uint32_t*)(Wih + (size_t)r * kHD);
#pragma unroll
    for (int j = 0; j < 64; ++j) wih[j] = pw[j];
    uint32_t whh[32];
    const uint32_t* ph = (const uint32_t*)(Whh + (size_t)r * kHL);
#pragma unroll
    for (int j = 0; j < 32; ++j) whh[j] = ph[j];
    const float bias = bf2f(bih[r]) + bf2f(bhh[r]);

    float c_st = 0.f;
    if (r < kHL) hs[r] = 0.f;
    __syncthreads();

    for (int t = 0; t < kT; ++t) {
        const size_t g = (size_t)b * kT + t;
        if (r < kHD) {
            if (use_part) {
                const float* ps = part + g * kNB * kHD + r;
                float v = ps[0];
#pragma unroll
                for (int k = 1; k < kNB; ++k) v = fmaxf(v, ps[(size_t)k * kHD]);
                xt[r] = v;
            } else {
                xt[r] = pooled[g * kHD + r];
            }
        }
        __syncthreads();
        float a0 = 0.f, a1 = 0.f, a2 = 0.f, a3 = 0.f;
#pragma unroll
        for (int j = 0; j < 64; j += 4) {
            uint32_t u0 = wih[j], u1 = wih[j + 1], u2 = wih[j + 2], u3 = wih[j + 3];
            a0 += blo(u0) * xt[2 * j + 0] + bhi(u0) * xt[2 * j + 1];
            a1 += blo(u1) * xt[2 * j + 2] + bhi(u1) * xt[2 * j + 3];
            a2 += blo(u2) * xt[2 * j + 4] + bhi(u2) * xt[2 * j + 5];
            a3 += blo(u3) * xt[2 * j + 6] + bhi(u3) * xt[2 * j + 7];
        }
#pragma unroll
        for (int j = 0; j < 32; j += 4) {
            uint32_t u0 = whh[j], u1 = whh[j + 1], u2 = whh[j + 2], u3 = whh[j + 3];
            a0 += blo(u0) * hs[2 * j + 0] + bhi(u0) * hs[2 * j + 1];
            a1 += blo(u1) * hs[2 * j + 2] + bhi(u1) * hs[2 * j + 3];
            a2 += blo(u2) * hs[2 * j + 4] + bhi(u2) * hs[2 * j + 5];
            a3 += blo(u3) * hs[2 * j + 6] + bhi(u3) * hs[2 * j + 7];
        }
        gates[r] = bias + (a0 + a1) + (a2 + a3);
        __syncthreads();
        if (r < kHL) {
            const float iv = sigm(gates[r]);
            const float fv = sigm(gates[kHL + r]);
            const float gv = tanhf(gates[2 * kHL + r]);
            const float ov = sigm(gates[3 * kHL + r]);
            c_st = fv * c_st + iv * gv;
            hs[r] = ov * tanhf(c_st);
        }
        __syncthreads();
    }
    if (r < kOUT) {
        float acc = bf2f(bclf[r]);
#pragma unroll
        for (int k = 0; k < kHL; ++k) acc += hs[k] * bf2f(Wclf[r * kHL + k]);
        if (*flag) ((float*)out)[b * kOUT + r] = acc;
        else ((__hip_bfloat16*)out)[b * kOUT + r] = __float2bfloat16(acc);
    }
}

// ---------------------------------------------------------------------------
extern "C" void kernel_launch(void* const* d_in, const int* in_sizes, int n_in,
                              void* d_out, int out_size, void* d_ws, size_t ws_size,
                              hipStream_t stream) {
    const int* ei = (const int*)d_in[1];

    char* ws = (char*)d_ws;
    int*            flag   = (int*)(ws + OFF_FLAG);
    int*            rowdeg = (int*)(ws + OFF_ROW);
    int*            colv   = (int*)(ws + OFF_COL);
    unsigned int*   pooled = (unsigned int*)(ws + OFF_POOL);
    unsigned short* canon  = (unsigned short*)(ws + OFF_CANON);

    unsigned short* cBg   = canon + CX_BG;
    unsigned short* cWih  = canon + CX_WIH;
    unsigned short* cWhh  = canon + CX_WHH;
    unsigned short* cBih  = canon + CX_BIH;
    unsigned short* cBhh  = canon + CX_BHH;
    unsigned short* cWclf = canon + CX_WCLF;
    unsigned short* cBclf = canon + CX_BCLF;

    float*          a_s = (float*)(ws + OFF_AS);
    float*          a_d = (float*)(ws + OFF_AS + (size_t)kG * 16000);
    unsigned short* xp  = (unsigned short*)(ws + OFF_AS + (size_t)kG * 32000);

    // ws_size is fixed per session -> flags constant -> graph-capture safe
    const int use_part   = (ws_size >= OFF_PPART + PPART_BYTES) ? 1 : 0;
    const int use_bucket = (ws_size >= OFF_BUCKET + BUCKET_BYTES) ? 1 : 0;
    float* part   = (float*)(ws + OFF_PPART);
    int*   bucket = (int*)(ws + OFF_BUCKET);

    ConvArgs ca;
    const int sizes[10] = {2048, 128, 128, 128, 32768, 16384, 256, 256, 512, 8};
    const int which[10] = {2, 3, 4, 5, 6, 7, 8, 9, 10, 11};
    for (int i = 0; i < 10; ++i) {
        ca.src[i] = (const unsigned short*)d_in[which[i]];
        ca.n[i] = sizes[i];
    }

    // zero deg (bucket path) — 4 KB, graph-capture-safe memset node
    hipMemsetAsync(ws + OFF_ROW, 0, 4096, stream);

    mega_setup<<<kSetupBlocks + kPre, 256, 0, stream>>>(
        d_in[0], ei, ca,
        (const unsigned short*)d_in[2], (const unsigned short*)d_in[3],
        (const unsigned short*)d_in[4],
        flag, rowdeg, colv, bucket, use_bucket, canon, xp, a_s, a_d, pooled);
    gat_aggregate<<<kG * kNB, 256, 0, stream>>>(rowdeg, colv, bucket, use_bucket,
                                                xp, a_s, a_d, cBg,
                                                pooled, part, use_part);
    lstm_head<<<kB, 256, 0, stream>>>((const float*)pooled, part, use_part,
                                      cWih, cWhh, cBih, cBhh,
                                      cWclf, cBclf, flag, d_out);
}